// Round 2
// baseline (493.896 us; speedup 1.0000x reference)
//
#include <hip/hip_runtime.h>

#define HID 128
#define NPG 1000
#define NGRAPH 100
#define NNODES (NPG * NGRAPH)      // 100000
#define DEG 8
#define LN_EPS 1e-5f

// ---------------------------------------------------------------------------
// K1: h = relu(x[0:2N] @ W^T + b) via split-fp16 MFMA (3-term: hi*hi + lo*hi
// + hi*lo, fp32 accumulate -> ~2^-22 relative error, fp32-equivalent here).
// S rows (r < N) go to outS (= out), I rows (r >= N) go to outI (= d_ws when
// available) so the fused K2 can overwrite out[N..2N) with ln(dI) without
// racing other blocks' I-gathers.
//
// Block = 256 threads (4 waves, 2x2 wave grid), tile = 128 rows x 128 cols.
// K=128 staged in halves of 64: LDS = X(hi,lo)+W(hi,lo) = 4x16KB = 64 KB
// -> 2 blocks/CU. f16 tiles XOR-swizzled (idx ^= (row&7)<<3) so every
// ds_read_b128 / ds_write_b128 is <=2-way (free) per bank.
// ---------------------------------------------------------------------------
#define K1_ROWS 128

typedef _Float16 half8 __attribute__((ext_vector_type(8)));
typedef float f32x4 __attribute__((ext_vector_type(4)));

__device__ inline void cvt_split(const float4 a, const float4 b,
                                 half8& hi, half8& lo)
{
    float v[8] = {a.x, a.y, a.z, a.w, b.x, b.y, b.z, b.w};
    #pragma unroll
    for (int i = 0; i < 8; ++i) {
        _Float16 h = (_Float16)v[i];          // RNE
        hi[i] = h;
        lo[i] = (_Float16)(v[i] - (float)h);  // remainder exact in f32
    }
}

__global__ __launch_bounds__(256, 2) void k_gemm_relu(
    const float* __restrict__ x, const float* __restrict__ W,
    const float* __restrict__ bias, float* __restrict__ outS,
    float* __restrict__ outI, int nrows)
{
    __shared__ alignas(16) _Float16 Xh[K1_ROWS * 64];
    __shared__ alignas(16) _Float16 Xl[K1_ROWS * 64];
    __shared__ alignas(16) _Float16 Wh[HID * 64];
    __shared__ alignas(16) _Float16 Wl[HID * 64];

    const int tid  = threadIdx.x;
    const int lane = tid & 63;
    const int w    = tid >> 6;
    const int wr   = (w >> 1) * 64;   // wave row offset in tile
    const int wc   = (w & 1) * 64;    // wave col offset
    const int r0   = blockIdx.x * K1_ROWS;

    f32x4 acc[4][4];
    #pragma unroll
    for (int i = 0; i < 4; ++i)
        #pragma unroll
        for (int j = 0; j < 4; ++j)
            acc[i][j] = (f32x4){0.f, 0.f, 0.f, 0.f};

    const int l15 = lane & 15;
    const int lg  = lane >> 4;       // k-group 0..3
    const int swz = (lane & 7) << 3; // row&7 == lane&7 for all frag rows/cols

    for (int kh = 0; kh < 2; ++kh) {
        if (kh) __syncthreads();

        // ---- stage X half-tile: 128 rows x 64 k, fp32 -> (hi,lo) f16 ----
        #pragma unroll
        for (int it = 0; it < 4; ++it) {
            int chunk = tid + it * 256;      // 1024 chunks of 8 halves
            int row = chunk >> 3, kg = chunk & 7;
            const float* gp = &x[(size_t)(r0 + row) * HID + kh * 64 + kg * 8];
            float4 a = reinterpret_cast<const float4*>(gp)[0];
            float4 b = reinterpret_cast<const float4*>(gp)[1];
            half8 hi, lo; cvt_split(a, b, hi, lo);
            int widx = (row * 64 + kg * 8) ^ ((row & 7) << 3);
            *reinterpret_cast<half8*>(&Xh[widx]) = hi;
            *reinterpret_cast<half8*>(&Xl[widx]) = lo;
        }
        // ---- stage W half-tile: 128 out-cols x 64 k ----
        #pragma unroll
        for (int it = 0; it < 4; ++it) {
            int chunk = tid + it * 256;
            int row = chunk >> 3, kg = chunk & 7;
            const float* gp = &W[(size_t)row * HID + kh * 64 + kg * 8];
            float4 a = reinterpret_cast<const float4*>(gp)[0];
            float4 b = reinterpret_cast<const float4*>(gp)[1];
            half8 hi, lo; cvt_split(a, b, hi, lo);
            int widx = (row * 64 + kg * 8) ^ ((row & 7) << 3);
            *reinterpret_cast<half8*>(&Wh[widx]) = hi;
            *reinterpret_cast<half8*>(&Wl[widx]) = lo;
        }
        __syncthreads();

        // ---- compute: 2 kb-steps of K=32, 48 MFMA each ----
        #pragma unroll
        for (int kb = 0; kb < 2; ++kb) {
            half8 ah[4], al[4], bh[4], bl[4];
            #pragma unroll
            for (int t = 0; t < 4; ++t) {
                int arow = wr + t * 16 + l15;
                int aidx = (arow * 64 + kb * 32 + lg * 8) ^ swz;
                ah[t] = *reinterpret_cast<const half8*>(&Xh[aidx]);
                al[t] = *reinterpret_cast<const half8*>(&Xl[aidx]);
                int bcol = wc + t * 16 + l15;
                int bidx = (bcol * 64 + kb * 32 + lg * 8) ^ swz;
                bh[t] = *reinterpret_cast<const half8*>(&Wh[bidx]);
                bl[t] = *reinterpret_cast<const half8*>(&Wl[bidx]);
            }
            #pragma unroll
            for (int rt = 0; rt < 4; ++rt)
                #pragma unroll
                for (int ct = 0; ct < 4; ++ct) {
                    acc[rt][ct] = __builtin_amdgcn_mfma_f32_16x16x32_f16(
                        ah[rt], bh[ct], acc[rt][ct], 0, 0, 0);
                    acc[rt][ct] = __builtin_amdgcn_mfma_f32_16x16x32_f16(
                        al[rt], bh[ct], acc[rt][ct], 0, 0, 0);
                    acc[rt][ct] = __builtin_amdgcn_mfma_f32_16x16x32_f16(
                        ah[rt], bl[ct], acc[rt][ct], 0, 0, 0);
                }
        }
    }

    // ---- epilogue: bias + relu + store (64B-coalesced per 16-lane group) ----
    float bc[4];
    #pragma unroll
    for (int ct = 0; ct < 4; ++ct) bc[ct] = bias[wc + ct * 16 + l15];

    #pragma unroll
    for (int rt = 0; rt < 4; ++rt) {
        int rowb = r0 + wr + rt * 16 + lg * 4;
        #pragma unroll
        for (int j = 0; j < 4; ++j) {
            int r = rowb + j;
            if (r < nrows) {
                float* base = (r < NNODES)
                                  ? &outS[(size_t)r * HID]
                                  : &outI[(size_t)(r - NNODES) * HID];
                float* hp = base + wc + l15;
                #pragma unroll
                for (int ct = 0; ct < 4; ++ct)
                    hp[ct * 16] = fmaxf(acc[rt][ct][j] + bc[ct], 0.f);
            }
        }
    }
}

// ---------------------------------------------------------------------------
// K2 (fused): per-node AI gather + dS/dI/dR + LayerNorm + tail copy.
// 8 blocks/graph, 125 nodes each. LDS histogram -> scan -> scatter (local
// CSR), then wave-per-node: gather AI from Ibuf (registers only, never
// materialized), load S/I/tail rows, LN, write 4 output rows.
// Safe because I lives in Ibuf (workspace), so ln(dI) writes to out[N..2N)
// race with nothing; S rows are read only by their owning wave.
// ---------------------------------------------------------------------------
#define BPG  8
#define RPB  (NPG / BPG)    // 125
#define ECAP 1280           // expected 1000, sigma ~30 -> +9.5 sigma margin

__global__ __launch_bounds__(256) void k_agg_final(
    const float* __restrict__ x, const float* __restrict__ Sbuf,
    const float* __restrict__ Ibuf, const int* __restrict__ erow,
    const int* __restrict__ ecol, const float* __restrict__ lnw,
    const float* __restrict__ lnb, float* __restrict__ out)
{
    __shared__ int cnt[RPB];
    __shared__ int wp[RPB];
    __shared__ int scan[256];
    __shared__ int cols[ECAP];

    const int g     = blockIdx.x / BPG;
    const int q     = blockIdx.x % BPG;
    const int row0  = q * RPB;
    const int nbase = g * NPG;
    const int ebase = g * (NPG * DEG);
    const int tid   = threadIdx.x;

    if (tid < RPB) cnt[tid] = 0;
    __syncthreads();

    // histogram of in-degree for our 125 rows
    for (int e = tid; e < NPG * DEG; e += 256) {
        int rl = erow[ebase + e] - nbase - row0;
        if ((unsigned)rl < (unsigned)RPB) atomicAdd(&cnt[rl], 1);
    }
    __syncthreads();

    // inclusive Hillis-Steele scan over 256 (cnt zero-padded)
    int v = (tid < RPB) ? cnt[tid] : 0;
    scan[tid] = v;
    __syncthreads();
    #pragma unroll
    for (int s = 1; s < 256; s <<= 1) {
        int t = (tid >= s) ? scan[tid - s] : 0;
        __syncthreads();
        scan[tid] += t;
        __syncthreads();
    }
    if (tid < RPB) wp[tid] = scan[tid] - cnt[tid];   // exclusive start
    __syncthreads();

    // scatter cols into per-row segments
    for (int e = tid; e < NPG * DEG; e += 256) {
        int rl = erow[ebase + e] - nbase - row0;
        if ((unsigned)rl < (unsigned)RPB) {
            int p = atomicAdd(&wp[rl], 1);
            if (p < ECAP) cols[p] = ecol[ebase + e];
        }
    }
    __syncthreads();

    const int wave = tid >> 6, lane = tid & 63;
    const int c = lane * 2;
    const size_t N = NNODES;

    const float2 lw = *reinterpret_cast<const float2*>(&lnw[c]);
    const float2 lb = *reinterpret_cast<const float2*>(&lnb[c]);

    auto ln_store = [&](float2 vv, float* dst) {
        float s = vv.x + vv.y;
        #pragma unroll
        for (int m = 1; m < 64; m <<= 1) s += __shfl_xor(s, m);
        const float mean = s * (1.f / 128.f);
        const float dx = vv.x - mean, dy = vv.y - mean;
        float qq = dx * dx + dy * dy;
        #pragma unroll
        for (int m = 1; m < 64; m <<= 1) qq += __shfl_xor(qq, m);
        const float rs = rsqrtf(qq * (1.f / 128.f) + LN_EPS);
        float2 o;
        o.x = dx * rs * lw.x + lb.x;
        o.y = dy * rs * lw.y + lb.y;
        *reinterpret_cast<float2*>(dst) = o;
    };

    for (int n = wave; n < RPB; n += 4) {
        const size_t gn = (size_t)(nbase + row0 + n);

        // issue own-row loads early (independent of the gather)
        float2 Sv = *reinterpret_cast<const float2*>(&Sbuf[gn * HID + c]);
        float2 Iv = *reinterpret_cast<const float2*>(&Ibuf[gn * HID + c]);
        float2 T  = *reinterpret_cast<const float2*>(&x[(3 * N + gn) * HID + c]);

        // gather-accumulate AI (float2 per lane = full 512B row, 4-deep ILP)
        int deg = cnt[n];
        int end = wp[n];            // == start + deg after scatter
        int j   = end - deg;
        float ax = 0.f, ay = 0.f;
        for (; j + 4 <= end; j += 4) {
            int c0 = cols[j], c1 = cols[j + 1], c2 = cols[j + 2], c3 = cols[j + 3];
            float2 v0 = *reinterpret_cast<const float2*>(&Ibuf[(size_t)c0 * HID + c]);
            float2 v1 = *reinterpret_cast<const float2*>(&Ibuf[(size_t)c1 * HID + c]);
            float2 v2 = *reinterpret_cast<const float2*>(&Ibuf[(size_t)c2 * HID + c]);
            float2 v3 = *reinterpret_cast<const float2*>(&Ibuf[(size_t)c3 * HID + c]);
            ax += v0.x + v1.x + v2.x + v3.x;
            ay += v0.y + v1.y + v2.y + v3.y;
        }
        for (; j < end; j++) {
            float2 v0 = *reinterpret_cast<const float2*>(&Ibuf[(size_t)cols[j] * HID + c]);
            ax += v0.x; ay += v0.y;
        }

        // beta/gam are columns 0,1 of the tail row = lane 0's float2
        const float beta = __shfl(T.x, 0);
        const float gam  = __shfl(T.y, 0);

        float2 dS, dI, dR;
        dS.x = -beta * (ax * Sv.x);
        dS.y = -beta * (ay * Sv.y);
        dI.x = -dS.x - gam * Iv.x;
        dI.y = -dS.y - gam * Iv.y;
        dR.x = gam * Iv.x;
        dR.y = gam * Iv.y;

        ln_store(dS, &out[gn * HID + c]);
        ln_store(dI, &out[(N + gn) * HID + c]);
        ln_store(dR, &out[(2 * N + gn) * HID + c]);
        *reinterpret_cast<float2*>(&out[(3 * N + gn) * HID + c]) = T;
    }
}

// ---------------------------------------------------------------------------
// Fallback path (ws too small): original K2 (AI materialized) + K3.
// ---------------------------------------------------------------------------
__global__ __launch_bounds__(256) void k_aggregate(
    const float* __restrict__ I, const int* __restrict__ erow,
    const int* __restrict__ ecol, float* __restrict__ AI)
{
    __shared__ int cnt[RPB];
    __shared__ int wp[RPB];
    __shared__ int scan[256];
    __shared__ int cols[ECAP];

    const int g     = blockIdx.x / BPG;
    const int q     = blockIdx.x % BPG;
    const int row0  = q * RPB;
    const int nbase = g * NPG;
    const int ebase = g * (NPG * DEG);
    const int tid   = threadIdx.x;

    if (tid < RPB) cnt[tid] = 0;
    __syncthreads();

    for (int e = tid; e < NPG * DEG; e += 256) {
        int rl = erow[ebase + e] - nbase - row0;
        if ((unsigned)rl < (unsigned)RPB) atomicAdd(&cnt[rl], 1);
    }
    __syncthreads();

    int v = (tid < RPB) ? cnt[tid] : 0;
    scan[tid] = v;
    __syncthreads();
    #pragma unroll
    for (int s = 1; s < 256; s <<= 1) {
        int t = (tid >= s) ? scan[tid - s] : 0;
        __syncthreads();
        scan[tid] += t;
        __syncthreads();
    }
    if (tid < RPB) wp[tid] = scan[tid] - cnt[tid];
    __syncthreads();

    for (int e = tid; e < NPG * DEG; e += 256) {
        int rl = erow[ebase + e] - nbase - row0;
        if ((unsigned)rl < (unsigned)RPB) {
            int p = atomicAdd(&wp[rl], 1);
            if (p < ECAP) cols[p] = ecol[ebase + e];
        }
    }
    __syncthreads();

    const int wave = tid >> 6, lane = tid & 63;
    const int c = lane * 2;
    for (int n = wave; n < RPB; n += 4) {
        int deg = cnt[n];
        int end = wp[n];
        int j   = end - deg;
        float ax = 0.f, ay = 0.f;
        for (; j + 4 <= end; j += 4) {
            int c0 = cols[j], c1 = cols[j + 1], c2 = cols[j + 2], c3 = cols[j + 3];
            float2 v0 = *reinterpret_cast<const float2*>(&I[(size_t)c0 * HID + c]);
            float2 v1 = *reinterpret_cast<const float2*>(&I[(size_t)c1 * HID + c]);
            float2 v2 = *reinterpret_cast<const float2*>(&I[(size_t)c2 * HID + c]);
            float2 v3 = *reinterpret_cast<const float2*>(&I[(size_t)c3 * HID + c]);
            ax += v0.x + v1.x + v2.x + v3.x;
            ay += v0.y + v1.y + v2.y + v3.y;
        }
        for (; j < end; j++) {
            float2 v0 = *reinterpret_cast<const float2*>(&I[(size_t)cols[j] * HID + c]);
            ax += v0.x; ay += v0.y;
        }
        float2 o; o.x = ax; o.y = ay;
        *reinterpret_cast<float2*>(&AI[(size_t)(nbase + row0 + n) * HID + c]) = o;
    }
}

__global__ __launch_bounds__(256) void k_final(
    const float* __restrict__ x, const float* __restrict__ lnw,
    const float* __restrict__ lnb, float* __restrict__ out)
{
    const int wave = threadIdx.x >> 6;
    const int lane = threadIdx.x & 63;
    const size_t i = (size_t)blockIdx.x * 4 + wave;
    const int c    = lane * 2;
    const size_t N = NNODES;

    float2 S  = *reinterpret_cast<const float2*>(&out[i * HID + c]);
    float2 I2 = *reinterpret_cast<const float2*>(&out[(N + i) * HID + c]);
    float2 A  = *reinterpret_cast<const float2*>(&out[(2 * N + i) * HID + c]);

    const float beta = x[(3 * N + i) * HID + 0];
    const float gam  = x[(3 * N + i) * HID + 1];

    float2 dS, dI, dR;
    dS.x = -beta * (A.x * S.x);
    dS.y = -beta * (A.y * S.y);
    dI.x = -dS.x - gam * I2.x;
    dI.y = -dS.y - gam * I2.y;
    dR.x = gam * I2.x;
    dR.y = gam * I2.y;

    const float2 lw = *reinterpret_cast<const float2*>(&lnw[c]);
    const float2 lb = *reinterpret_cast<const float2*>(&lnb[c]);

    auto ln_store = [&](float2 v, float* dst) {
        float s = v.x + v.y;
        #pragma unroll
        for (int m = 1; m < 64; m <<= 1) s += __shfl_xor(s, m);
        const float mean = s * (1.f / 128.f);
        const float dx = v.x - mean, dy = v.y - mean;
        float q = dx * dx + dy * dy;
        #pragma unroll
        for (int m = 1; m < 64; m <<= 1) q += __shfl_xor(q, m);
        const float rs = rsqrtf(q * (1.f / 128.f) + LN_EPS);
        float2 o;
        o.x = dx * rs * lw.x + lb.x;
        o.y = dy * rs * lw.y + lb.y;
        *reinterpret_cast<float2*>(dst) = o;
    };

    ln_store(dS, &out[i * HID + c]);
    ln_store(dI, &out[(N + i) * HID + c]);
    ln_store(dR, &out[(2 * N + i) * HID + c]);

    const float2 t2 =
        *reinterpret_cast<const float2*>(&x[(3 * N + i) * HID + c]);
    *reinterpret_cast<float2*>(&out[(3 * N + i) * HID + c]) = t2;
}

// ---------------------------------------------------------------------------
extern "C" void kernel_launch(void* const* d_in, const int* in_sizes, int n_in,
                              void* d_out, int out_size, void* d_ws,
                              size_t ws_size, hipStream_t stream)
{
    // inputs: 0:t 1:x 2:edge_row 3:edge_col 4:W 5:b 6:ln_w 7:ln_b
    const float* x   = (const float*)d_in[1];
    const int* erow  = (const int*)d_in[2];
    const int* ecol  = (const int*)d_in[3];
    const float* W   = (const float*)d_in[4];
    const float* b   = (const float*)d_in[5];
    const float* lnw = (const float*)d_in[6];
    const float* lnb = (const float*)d_in[7];
    float* out = (float*)d_out;

    const int nrows = 2 * NNODES;                    // R rows never needed
    const size_t ineed = (size_t)NNODES * HID * sizeof(float);

    if (d_ws != nullptr && ws_size >= ineed) {
        // Fused path: I rows -> workspace; AI never materialized.
        float* Iws = (float*)d_ws;
        k_gemm_relu<<<(nrows + K1_ROWS - 1) / K1_ROWS, 256, 0, stream>>>(
            x, W, b, out, Iws, nrows);
        k_agg_final<<<NGRAPH * BPG, 256, 0, stream>>>(
            x, out, Iws, erow, ecol, lnw, lnb, out);
    } else {
        // Fallback: original 3-kernel path, I rows in out[N..2N).
        float* Iptr  = out + (size_t)NNODES * HID;
        float* AIptr = out + (size_t)2 * NNODES * HID;
        k_gemm_relu<<<(nrows + K1_ROWS - 1) / K1_ROWS, 256, 0, stream>>>(
            x, W, b, out, Iptr, nrows);
        k_aggregate<<<NGRAPH * BPG, 256, 0, stream>>>(Iptr, erow, ecol, AIptr);
        k_final<<<NNODES / 4, 256, 0, stream>>>(x, lnw, lnb, out);
    }
}

// Round 3
// 469.728 us; speedup vs baseline: 1.0515x; 1.0515x over previous
//
#include <hip/hip_runtime.h>

#define HID 128
#define NPG 1000
#define NGRAPH 100
#define NNODES (NPG * NGRAPH)      // 100000
#define DEG 8
#define LN_EPS 1e-5f

// ---------------------------------------------------------------------------
// K1: h = relu(x[0:2N] @ W^T + b) via split-fp16 MFMA (3-term: hi*hi + lo*hi
// + hi*lo, fp32 accumulate -> ~2^-22 relative error, fp32-equivalent here).
// S rows (r < N) go to outS (= out), I rows (r >= N) go to outI (= d_ws when
// available) so the fused K2 can overwrite out[N..2N) with ln(dI) without
// racing other blocks' I-gathers.
//
// Block = 256 threads (4 waves, 2x2 wave grid), tile = 128 rows x 128 cols.
// K=128 staged in halves of 64: LDS = X(hi,lo)+W(hi,lo) = 4x16KB = 64 KB
// -> 2 blocks/CU. f16 tiles XOR-swizzled (idx ^= (row&7)<<3) so every
// ds_read_b128 / ds_write_b128 is <=2-way (free) per bank.
// ---------------------------------------------------------------------------
#define K1_ROWS 128

typedef _Float16 half8 __attribute__((ext_vector_type(8)));
typedef float f32x4 __attribute__((ext_vector_type(4)));

__device__ inline void cvt_split(const float4 a, const float4 b,
                                 half8& hi, half8& lo)
{
    float v[8] = {a.x, a.y, a.z, a.w, b.x, b.y, b.z, b.w};
    #pragma unroll
    for (int i = 0; i < 8; ++i) {
        _Float16 h = (_Float16)v[i];          // RNE
        hi[i] = h;
        lo[i] = (_Float16)(v[i] - (float)h);  // remainder exact in f32
    }
}

__global__ __launch_bounds__(256, 2) void k_gemm_relu(
    const float* __restrict__ x, const float* __restrict__ W,
    const float* __restrict__ bias, float* __restrict__ outS,
    float* __restrict__ outI, int nrows)
{
    __shared__ alignas(16) _Float16 Xh[K1_ROWS * 64];
    __shared__ alignas(16) _Float16 Xl[K1_ROWS * 64];
    __shared__ alignas(16) _Float16 Wh[HID * 64];
    __shared__ alignas(16) _Float16 Wl[HID * 64];

    const int tid  = threadIdx.x;
    const int lane = tid & 63;
    const int w    = tid >> 6;
    const int wr   = (w >> 1) * 64;   // wave row offset in tile
    const int wc   = (w & 1) * 64;    // wave col offset
    const int r0   = blockIdx.x * K1_ROWS;

    f32x4 acc[4][4];
    #pragma unroll
    for (int i = 0; i < 4; ++i)
        #pragma unroll
        for (int j = 0; j < 4; ++j)
            acc[i][j] = (f32x4){0.f, 0.f, 0.f, 0.f};

    const int l15 = lane & 15;
    const int lg  = lane >> 4;       // k-group 0..3
    const int swz = (lane & 7) << 3; // row&7 == lane&7 for all frag rows/cols

    for (int kh = 0; kh < 2; ++kh) {
        if (kh) __syncthreads();

        // ---- stage X half-tile: 128 rows x 64 k, fp32 -> (hi,lo) f16 ----
        #pragma unroll
        for (int it = 0; it < 4; ++it) {
            int chunk = tid + it * 256;      // 1024 chunks of 8 halves
            int row = chunk >> 3, kg = chunk & 7;
            const float* gp = &x[(size_t)(r0 + row) * HID + kh * 64 + kg * 8];
            float4 a = reinterpret_cast<const float4*>(gp)[0];
            float4 b = reinterpret_cast<const float4*>(gp)[1];
            half8 hi, lo; cvt_split(a, b, hi, lo);
            int widx = (row * 64 + kg * 8) ^ ((row & 7) << 3);
            *reinterpret_cast<half8*>(&Xh[widx]) = hi;
            *reinterpret_cast<half8*>(&Xl[widx]) = lo;
        }
        // ---- stage W half-tile: 128 out-cols x 64 k ----
        #pragma unroll
        for (int it = 0; it < 4; ++it) {
            int chunk = tid + it * 256;
            int row = chunk >> 3, kg = chunk & 7;
            const float* gp = &W[(size_t)row * HID + kh * 64 + kg * 8];
            float4 a = reinterpret_cast<const float4*>(gp)[0];
            float4 b = reinterpret_cast<const float4*>(gp)[1];
            half8 hi, lo; cvt_split(a, b, hi, lo);
            int widx = (row * 64 + kg * 8) ^ ((row & 7) << 3);
            *reinterpret_cast<half8*>(&Wh[widx]) = hi;
            *reinterpret_cast<half8*>(&Wl[widx]) = lo;
        }
        __syncthreads();

        // ---- compute: 2 kb-steps of K=32, 48 MFMA each ----
        #pragma unroll
        for (int kb = 0; kb < 2; ++kb) {
            half8 ah[4], al[4], bh[4], bl[4];
            #pragma unroll
            for (int t = 0; t < 4; ++t) {
                int arow = wr + t * 16 + l15;
                int aidx = (arow * 64 + kb * 32 + lg * 8) ^ swz;
                ah[t] = *reinterpret_cast<const half8*>(&Xh[aidx]);
                al[t] = *reinterpret_cast<const half8*>(&Xl[aidx]);
                int bcol = wc + t * 16 + l15;
                int bidx = (bcol * 64 + kb * 32 + lg * 8) ^ swz;
                bh[t] = *reinterpret_cast<const half8*>(&Wh[bidx]);
                bl[t] = *reinterpret_cast<const half8*>(&Wl[bidx]);
            }
            #pragma unroll
            for (int rt = 0; rt < 4; ++rt)
                #pragma unroll
                for (int ct = 0; ct < 4; ++ct) {
                    acc[rt][ct] = __builtin_amdgcn_mfma_f32_16x16x32_f16(
                        ah[rt], bh[ct], acc[rt][ct], 0, 0, 0);
                    acc[rt][ct] = __builtin_amdgcn_mfma_f32_16x16x32_f16(
                        al[rt], bh[ct], acc[rt][ct], 0, 0, 0);
                    acc[rt][ct] = __builtin_amdgcn_mfma_f32_16x16x32_f16(
                        ah[rt], bl[ct], acc[rt][ct], 0, 0, 0);
                }
        }
    }

    // ---- epilogue: bias + relu + store (64B-coalesced per 16-lane group) ----
    float bc[4];
    #pragma unroll
    for (int ct = 0; ct < 4; ++ct) bc[ct] = bias[wc + ct * 16 + l15];

    #pragma unroll
    for (int rt = 0; rt < 4; ++rt) {
        int rowb = r0 + wr + rt * 16 + lg * 4;
        #pragma unroll
        for (int j = 0; j < 4; ++j) {
            int r = rowb + j;
            if (r < nrows) {
                float* base = (r < NNODES)
                                  ? &outS[(size_t)r * HID]
                                  : &outI[(size_t)(r - NNODES) * HID];
                float* hp = base + wc + l15;
                #pragma unroll
                for (int ct = 0; ct < 4; ++ct)
                    hp[ct * 16] = fmaxf(acc[rt][ct][j] + bc[ct], 0.f);
            }
        }
    }
}

// ---------------------------------------------------------------------------
// K2 (fused): per-node AI gather + dS/dI/dR + LayerNorm + tail copy.
// 8 blocks/graph, 125 nodes each, 512 threads (8 waves) per block.
//
// XCD co-location: dispatch round-robins blockIdx%8 across the 8 XCDs, so we
// remap (xcd = bi&7, slot = bi>>3) -> id = xcd*100+slot; g = id>>3, q = id&7.
// Graph g's 8 blocks then occupy consecutive ids on ONE XCD (96/100 graphs
// fully co-located) -> its 512KB I-slice + 64KB edge list are fetched from
// HBM once and served from that XCD's L2 for the other 7 blocks. Bijective
// (800 = 8 * 100). Heuristic only: wrong XCD mapping costs speed, not
// correctness.
//
// 8 waves/block raises occupancy 12.5 -> 25 waves/CU for latency hiding of
// the random 512B row gathers.
// ---------------------------------------------------------------------------
#define BPG  8
#define RPB  (NPG / BPG)    // 125
#define ECAP 1280           // expected 1000, sigma ~30 -> +9.5 sigma margin

__global__ __launch_bounds__(512) void k_agg_final(
    const float* __restrict__ x, const float* __restrict__ Sbuf,
    const float* __restrict__ Ibuf, const int* __restrict__ erow,
    const int* __restrict__ ecol, const float* __restrict__ lnw,
    const float* __restrict__ lnb, float* __restrict__ out)
{
    __shared__ int cnt[RPB];
    __shared__ int wp[RPB];
    __shared__ int scan[128];
    __shared__ int cols[ECAP];

    const int bi   = blockIdx.x;
    const int id   = (bi & 7) * (NGRAPH * BPG / 8) + (bi >> 3);
    const int g    = id >> 3;
    const int q    = id & 7;
    const int row0  = q * RPB;
    const int nbase = g * NPG;
    const int ebase = g * (NPG * DEG);
    const int tid   = threadIdx.x;

    if (tid < RPB) cnt[tid] = 0;
    __syncthreads();

    // histogram of in-degree for our 125 rows
    for (int e = tid; e < NPG * DEG; e += 512) {
        int rl = erow[ebase + e] - nbase - row0;
        if ((unsigned)rl < (unsigned)RPB) atomicAdd(&cnt[rl], 1);
    }
    __syncthreads();

    // inclusive Hillis-Steele scan over 128 (cnt zero-padded)
    int v = (tid < RPB) ? cnt[tid] : 0;
    if (tid < 128) scan[tid] = v;
    __syncthreads();
    #pragma unroll
    for (int s = 1; s < 128; s <<= 1) {
        int t = (tid < 128 && tid >= s) ? scan[tid - s] : 0;
        __syncthreads();
        if (tid < 128) scan[tid] += t;
        __syncthreads();
    }
    if (tid < RPB) wp[tid] = scan[tid] - cnt[tid];   // exclusive start
    __syncthreads();

    // scatter cols into per-row segments
    for (int e = tid; e < NPG * DEG; e += 512) {
        int rl = erow[ebase + e] - nbase - row0;
        if ((unsigned)rl < (unsigned)RPB) {
            int p = atomicAdd(&wp[rl], 1);
            if (p < ECAP) cols[p] = ecol[ebase + e];
        }
    }
    __syncthreads();

    const int wave = tid >> 6, lane = tid & 63;
    const int c = lane * 2;
    const size_t N = NNODES;

    const float2 lw = *reinterpret_cast<const float2*>(&lnw[c]);
    const float2 lb = *reinterpret_cast<const float2*>(&lnb[c]);

    auto ln_store = [&](float2 vv, float* dst) {
        float s = vv.x + vv.y;
        #pragma unroll
        for (int m = 1; m < 64; m <<= 1) s += __shfl_xor(s, m);
        const float mean = s * (1.f / 128.f);
        const float dx = vv.x - mean, dy = vv.y - mean;
        float qq = dx * dx + dy * dy;
        #pragma unroll
        for (int m = 1; m < 64; m <<= 1) qq += __shfl_xor(qq, m);
        const float rs = rsqrtf(qq * (1.f / 128.f) + LN_EPS);
        float2 o;
        o.x = dx * rs * lw.x + lb.x;
        o.y = dy * rs * lw.y + lb.y;
        *reinterpret_cast<float2*>(dst) = o;
    };

    for (int n = wave; n < RPB; n += 8) {
        const size_t gn = (size_t)(nbase + row0 + n);

        // issue own-row loads early (independent of the gather)
        float2 Sv = *reinterpret_cast<const float2*>(&Sbuf[gn * HID + c]);
        float2 Iv = *reinterpret_cast<const float2*>(&Ibuf[gn * HID + c]);
        float2 T  = *reinterpret_cast<const float2*>(&x[(3 * N + gn) * HID + c]);

        // gather-accumulate AI (float2 per lane = full 512B row, 4-deep ILP)
        int deg = cnt[n];
        int end = wp[n];            // == start + deg after scatter
        int j   = end - deg;
        float ax = 0.f, ay = 0.f;
        for (; j + 4 <= end; j += 4) {
            int c0 = cols[j], c1 = cols[j + 1], c2 = cols[j + 2], c3 = cols[j + 3];
            float2 v0 = *reinterpret_cast<const float2*>(&Ibuf[(size_t)c0 * HID + c]);
            float2 v1 = *reinterpret_cast<const float2*>(&Ibuf[(size_t)c1 * HID + c]);
            float2 v2 = *reinterpret_cast<const float2*>(&Ibuf[(size_t)c2 * HID + c]);
            float2 v3 = *reinterpret_cast<const float2*>(&Ibuf[(size_t)c3 * HID + c]);
            ax += v0.x + v1.x + v2.x + v3.x;
            ay += v0.y + v1.y + v2.y + v3.y;
        }
        for (; j < end; j++) {
            float2 v0 = *reinterpret_cast<const float2*>(&Ibuf[(size_t)cols[j] * HID + c]);
            ax += v0.x; ay += v0.y;
        }

        // beta/gam are columns 0,1 of the tail row = lane 0's float2
        const float beta = __shfl(T.x, 0);
        const float gam  = __shfl(T.y, 0);

        float2 dS, dI, dR;
        dS.x = -beta * (ax * Sv.x);
        dS.y = -beta * (ay * Sv.y);
        dI.x = -dS.x - gam * Iv.x;
        dI.y = -dS.y - gam * Iv.y;
        dR.x = gam * Iv.x;
        dR.y = gam * Iv.y;

        ln_store(dS, &out[gn * HID + c]);
        ln_store(dI, &out[(N + gn) * HID + c]);
        ln_store(dR, &out[(2 * N + gn) * HID + c]);
        *reinterpret_cast<float2*>(&out[(3 * N + gn) * HID + c]) = T;
    }
}

// ---------------------------------------------------------------------------
// Fallback path (ws too small): original K2 (AI materialized) + K3.
// ---------------------------------------------------------------------------
__global__ __launch_bounds__(256) void k_aggregate(
    const float* __restrict__ I, const int* __restrict__ erow,
    const int* __restrict__ ecol, float* __restrict__ AI)
{
    __shared__ int cnt[RPB];
    __shared__ int wp[RPB];
    __shared__ int scan[256];
    __shared__ int cols[ECAP];

    const int g     = blockIdx.x / BPG;
    const int q     = blockIdx.x % BPG;
    const int row0  = q * RPB;
    const int nbase = g * NPG;
    const int ebase = g * (NPG * DEG);
    const int tid   = threadIdx.x;

    if (tid < RPB) cnt[tid] = 0;
    __syncthreads();

    for (int e = tid; e < NPG * DEG; e += 256) {
        int rl = erow[ebase + e] - nbase - row0;
        if ((unsigned)rl < (unsigned)RPB) atomicAdd(&cnt[rl], 1);
    }
    __syncthreads();

    int v = (tid < RPB) ? cnt[tid] : 0;
    scan[tid] = v;
    __syncthreads();
    #pragma unroll
    for (int s = 1; s < 256; s <<= 1) {
        int t = (tid >= s) ? scan[tid - s] : 0;
        __syncthreads();
        scan[tid] += t;
        __syncthreads();
    }
    if (tid < RPB) wp[tid] = scan[tid] - cnt[tid];
    __syncthreads();

    for (int e = tid; e < NPG * DEG; e += 256) {
        int rl = erow[ebase + e] - nbase - row0;
        if ((unsigned)rl < (unsigned)RPB) {
            int p = atomicAdd(&wp[rl], 1);
            if (p < ECAP) cols[p] = ecol[ebase + e];
        }
    }
    __syncthreads();

    const int wave = tid >> 6, lane = tid & 63;
    const int c = lane * 2;
    for (int n = wave; n < RPB; n += 4) {
        int deg = cnt[n];
        int end = wp[n];
        int j   = end - deg;
        float ax = 0.f, ay = 0.f;
        for (; j + 4 <= end; j += 4) {
            int c0 = cols[j], c1 = cols[j + 1], c2 = cols[j + 2], c3 = cols[j + 3];
            float2 v0 = *reinterpret_cast<const float2*>(&I[(size_t)c0 * HID + c]);
            float2 v1 = *reinterpret_cast<const float2*>(&I[(size_t)c1 * HID + c]);
            float2 v2 = *reinterpret_cast<const float2*>(&I[(size_t)c2 * HID + c]);
            float2 v3 = *reinterpret_cast<const float2*>(&I[(size_t)c3 * HID + c]);
            ax += v0.x + v1.x + v2.x + v3.x;
            ay += v0.y + v1.y + v2.y + v3.y;
        }
        for (; j < end; j++) {
            float2 v0 = *reinterpret_cast<const float2*>(&I[(size_t)cols[j] * HID + c]);
            ax += v0.x; ay += v0.y;
        }
        float2 o; o.x = ax; o.y = ay;
        *reinterpret_cast<float2*>(&AI[(size_t)(nbase + row0 + n) * HID + c]) = o;
    }
}

__global__ __launch_bounds__(256) void k_final(
    const float* __restrict__ x, const float* __restrict__ lnw,
    const float* __restrict__ lnb, float* __restrict__ out)
{
    const int wave = threadIdx.x >> 6;
    const int lane = threadIdx.x & 63;
    const size_t i = (size_t)blockIdx.x * 4 + wave;
    const int c    = lane * 2;
    const size_t N = NNODES;

    float2 S  = *reinterpret_cast<const float2*>(&out[i * HID + c]);
    float2 I2 = *reinterpret_cast<const float2*>(&out[(N + i) * HID + c]);
    float2 A  = *reinterpret_cast<const float2*>(&out[(2 * N + i) * HID + c]);

    const float beta = x[(3 * N + i) * HID + 0];
    const float gam  = x[(3 * N + i) * HID + 1];

    float2 dS, dI, dR;
    dS.x = -beta * (A.x * S.x);
    dS.y = -beta * (A.y * S.y);
    dI.x = -dS.x - gam * I2.x;
    dI.y = -dS.y - gam * I2.y;
    dR.x = gam * I2.x;
    dR.y = gam * I2.y;

    const float2 lw = *reinterpret_cast<const float2*>(&lnw[c]);
    const float2 lb = *reinterpret_cast<const float2*>(&lnb[c]);

    auto ln_store = [&](float2 v, float* dst) {
        float s = v.x + v.y;
        #pragma unroll
        for (int m = 1; m < 64; m <<= 1) s += __shfl_xor(s, m);
        const float mean = s * (1.f / 128.f);
        const float dx = v.x - mean, dy = v.y - mean;
        float q = dx * dx + dy * dy;
        #pragma unroll
        for (int m = 1; m < 64; m <<= 1) q += __shfl_xor(q, m);
        const float rs = rsqrtf(q * (1.f / 128.f) + LN_EPS);
        float2 o;
        o.x = dx * rs * lw.x + lb.x;
        o.y = dy * rs * lw.y + lb.y;
        *reinterpret_cast<float2*>(dst) = o;
    };

    ln_store(dS, &out[i * HID + c]);
    ln_store(dI, &out[(N + i) * HID + c]);
    ln_store(dR, &out[(2 * N + i) * HID + c]);

    const float2 t2 =
        *reinterpret_cast<const float2*>(&x[(3 * N + i) * HID + c]);
    *reinterpret_cast<float2*>(&out[(3 * N + i) * HID + c]) = t2;
}

// ---------------------------------------------------------------------------
extern "C" void kernel_launch(void* const* d_in, const int* in_sizes, int n_in,
                              void* d_out, int out_size, void* d_ws,
                              size_t ws_size, hipStream_t stream)
{
    // inputs: 0:t 1:x 2:edge_row 3:edge_col 4:W 5:b 6:ln_w 7:ln_b
    const float* x   = (const float*)d_in[1];
    const int* erow  = (const int*)d_in[2];
    const int* ecol  = (const int*)d_in[3];
    const float* W   = (const float*)d_in[4];
    const float* b   = (const float*)d_in[5];
    const float* lnw = (const float*)d_in[6];
    const float* lnb = (const float*)d_in[7];
    float* out = (float*)d_out;

    const int nrows = 2 * NNODES;                    // R rows never needed
    const size_t ineed = (size_t)NNODES * HID * sizeof(float);

    if (d_ws != nullptr && ws_size >= ineed) {
        // Fused path: I rows -> workspace; AI never materialized.
        float* Iws = (float*)d_ws;
        k_gemm_relu<<<(nrows + K1_ROWS - 1) / K1_ROWS, 256, 0, stream>>>(
            x, W, b, out, Iws, nrows);
        k_agg_final<<<NGRAPH * BPG, 512, 0, stream>>>(
            x, out, Iws, erow, ecol, lnw, lnb, out);
    } else {
        // Fallback: original 3-kernel path, I rows in out[N..2N).
        float* Iptr  = out + (size_t)NNODES * HID;
        float* AIptr = out + (size_t)2 * NNODES * HID;
        k_gemm_relu<<<(nrows + K1_ROWS - 1) / K1_ROWS, 256, 0, stream>>>(
            x, W, b, out, Iptr, nrows);
        k_aggregate<<<NGRAPH * BPG, 256, 0, stream>>>(Iptr, erow, ecol, AIptr);
        k_final<<<NNODES / 4, 256, 0, stream>>>(x, lnw, lnb, out);
    }
}

// Round 4
// 460.063 us; speedup vs baseline: 1.0735x; 1.0210x over previous
//
#include <hip/hip_runtime.h>

#define HID 128
#define NPG 1000
#define NGRAPH 100
#define NNODES (NPG * NGRAPH)      // 100000
#define DEG 8
#define LN_EPS 1e-5f

// ---------------------------------------------------------------------------
// K1: h = relu(x[0:2N] @ W^T + b) via split-fp16 MFMA (3-term: hi*hi + lo*hi
// + hi*lo, fp32 accumulate -> ~2^-22 relative error, fp32-equivalent here).
// S rows (r < N) go to outS (= out), I rows (r >= N) go to outI (= d_ws when
// available) so the fused K2 can overwrite out[N..2N) with ln(dI) without
// racing other blocks' I-gathers.  ~55 us, near its 49 us roofline.
// ---------------------------------------------------------------------------
#define K1_ROWS 128

typedef _Float16 half8 __attribute__((ext_vector_type(8)));
typedef float f32x4 __attribute__((ext_vector_type(4)));

__device__ inline void cvt_split(const float4 a, const float4 b,
                                 half8& hi, half8& lo)
{
    float v[8] = {a.x, a.y, a.z, a.w, b.x, b.y, b.z, b.w};
    #pragma unroll
    for (int i = 0; i < 8; ++i) {
        _Float16 h = (_Float16)v[i];          // RNE
        hi[i] = h;
        lo[i] = (_Float16)(v[i] - (float)h);  // remainder exact in f32
    }
}

__global__ __launch_bounds__(256, 2) void k_gemm_relu(
    const float* __restrict__ x, const float* __restrict__ W,
    const float* __restrict__ bias, float* __restrict__ outS,
    float* __restrict__ outI, int nrows)
{
    __shared__ alignas(16) _Float16 Xh[K1_ROWS * 64];
    __shared__ alignas(16) _Float16 Xl[K1_ROWS * 64];
    __shared__ alignas(16) _Float16 Wh[HID * 64];
    __shared__ alignas(16) _Float16 Wl[HID * 64];

    const int tid  = threadIdx.x;
    const int lane = tid & 63;
    const int w    = tid >> 6;
    const int wr   = (w >> 1) * 64;   // wave row offset in tile
    const int wc   = (w & 1) * 64;    // wave col offset
    const int r0   = blockIdx.x * K1_ROWS;

    f32x4 acc[4][4];
    #pragma unroll
    for (int i = 0; i < 4; ++i)
        #pragma unroll
        for (int j = 0; j < 4; ++j)
            acc[i][j] = (f32x4){0.f, 0.f, 0.f, 0.f};

    const int l15 = lane & 15;
    const int lg  = lane >> 4;       // k-group 0..3
    const int swz = (lane & 7) << 3; // row&7 == lane&7 for all frag rows/cols

    for (int kh = 0; kh < 2; ++kh) {
        if (kh) __syncthreads();

        // ---- stage X half-tile: 128 rows x 64 k, fp32 -> (hi,lo) f16 ----
        #pragma unroll
        for (int it = 0; it < 4; ++it) {
            int chunk = tid + it * 256;      // 1024 chunks of 8 halves
            int row = chunk >> 3, kg = chunk & 7;
            const float* gp = &x[(size_t)(r0 + row) * HID + kh * 64 + kg * 8];
            float4 a = reinterpret_cast<const float4*>(gp)[0];
            float4 b = reinterpret_cast<const float4*>(gp)[1];
            half8 hi, lo; cvt_split(a, b, hi, lo);
            int widx = (row * 64 + kg * 8) ^ ((row & 7) << 3);
            *reinterpret_cast<half8*>(&Xh[widx]) = hi;
            *reinterpret_cast<half8*>(&Xl[widx]) = lo;
        }
        // ---- stage W half-tile: 128 out-cols x 64 k ----
        #pragma unroll
        for (int it = 0; it < 4; ++it) {
            int chunk = tid + it * 256;
            int row = chunk >> 3, kg = chunk & 7;
            const float* gp = &W[(size_t)row * HID + kh * 64 + kg * 8];
            float4 a = reinterpret_cast<const float4*>(gp)[0];
            float4 b = reinterpret_cast<const float4*>(gp)[1];
            half8 hi, lo; cvt_split(a, b, hi, lo);
            int widx = (row * 64 + kg * 8) ^ ((row & 7) << 3);
            *reinterpret_cast<half8*>(&Wh[widx]) = hi;
            *reinterpret_cast<half8*>(&Wl[widx]) = lo;
        }
        __syncthreads();

        // ---- compute: 2 kb-steps of K=32, 48 MFMA each ----
        #pragma unroll
        for (int kb = 0; kb < 2; ++kb) {
            half8 ah[4], al[4], bh[4], bl[4];
            #pragma unroll
            for (int t = 0; t < 4; ++t) {
                int arow = wr + t * 16 + l15;
                int aidx = (arow * 64 + kb * 32 + lg * 8) ^ swz;
                ah[t] = *reinterpret_cast<const half8*>(&Xh[aidx]);
                al[t] = *reinterpret_cast<const half8*>(&Xl[aidx]);
                int bcol = wc + t * 16 + l15;
                int bidx = (bcol * 64 + kb * 32 + lg * 8) ^ swz;
                bh[t] = *reinterpret_cast<const half8*>(&Wh[bidx]);
                bl[t] = *reinterpret_cast<const half8*>(&Wl[bidx]);
            }
            #pragma unroll
            for (int rt = 0; rt < 4; ++rt)
                #pragma unroll
                for (int ct = 0; ct < 4; ++ct) {
                    acc[rt][ct] = __builtin_amdgcn_mfma_f32_16x16x32_f16(
                        ah[rt], bh[ct], acc[rt][ct], 0, 0, 0);
                    acc[rt][ct] = __builtin_amdgcn_mfma_f32_16x16x32_f16(
                        al[rt], bh[ct], acc[rt][ct], 0, 0, 0);
                    acc[rt][ct] = __builtin_amdgcn_mfma_f32_16x16x32_f16(
                        ah[rt], bl[ct], acc[rt][ct], 0, 0, 0);
                }
        }
    }

    // ---- epilogue: bias + relu + store (64B-coalesced per 16-lane group) ----
    float bc[4];
    #pragma unroll
    for (int ct = 0; ct < 4; ++ct) bc[ct] = bias[wc + ct * 16 + l15];

    #pragma unroll
    for (int rt = 0; rt < 4; ++rt) {
        int rowb = r0 + wr + rt * 16 + lg * 4;
        #pragma unroll
        for (int j = 0; j < 4; ++j) {
            int r = rowb + j;
            if (r < nrows) {
                float* base = (r < NNODES)
                                  ? &outS[(size_t)r * HID]
                                  : &outI[(size_t)(r - NNODES) * HID];
                float* hp = base + wc + l15;
                #pragma unroll
                for (int ct = 0; ct < 4; ++ct)
                    hp[ct * 16] = fmaxf(acc[rt][ct][j] + bc[ct], 0.f);
            }
        }
    }
}

// ---------------------------------------------------------------------------
// K2 (fused): per-node AI gather + dS/dI/dR + LayerNorm + tail copy.
// 20 blocks/graph x 50 nodes, 256 threads (4 waves), grid 2000 -> 7.8
// blocks/CU against the 8-block capacity (launch_bounds(256,8) caps VGPR at
// 64 so 32 waves/CU is reachable).  Round-3 stalled at 54% occupancy with
// only 800 blocks — grid size was the limiter, not resources.
//
// 2 nodes per wave (one per 32-lane half, float4/lane = full 512B row):
// float4 gathers halve load-instruction count; LN reductions are 5 shfl
// steps over 32 lanes; mean+var fused in ONE pass (var = E[x^2]-mean^2,
// clamped; cancellation harmless at 0.03 abs tolerance).
//
// XCD co-location: id = (bi&7)*250 + bi>>3; g = id/20. Graph's 20 blocks
// occupy consecutive ids on one XCD (96/100 graphs) -> I-slice + edges hit
// that XCD's L2 after first fetch. Bijective (2000 = 8*250).
// ---------------------------------------------------------------------------
#define BPG2  20
#define RPB2  50            // rows per block
#define ECAP2 640           // mean 400, sigma ~19.5 -> +12 sigma margin

__global__ __launch_bounds__(256, 8) void k_agg_final(
    const float* __restrict__ x, const float* __restrict__ Sbuf,
    const float* __restrict__ Ibuf, const int* __restrict__ erow,
    const int* __restrict__ ecol, const float* __restrict__ lnw,
    const float* __restrict__ lnb, float* __restrict__ out)
{
    __shared__ int cnt[RPB2];
    __shared__ int wp[RPB2];
    __shared__ int scn[64];
    __shared__ int cols[ECAP2];

    const int bi    = blockIdx.x;
    const int id    = (bi & 7) * (NGRAPH * BPG2 / 8) + (bi >> 3);
    const int g     = id / BPG2;
    const int q     = id % BPG2;
    const int row0  = q * RPB2;
    const int nbase = g * NPG;
    const int ebase = g * (NPG * DEG);
    const int tid   = threadIdx.x;

    if (tid < RPB2) cnt[tid] = 0;
    __syncthreads();

    // histogram of in-degree for our 50 rows
    for (int e = tid; e < NPG * DEG; e += 256) {
        int rl = erow[ebase + e] - nbase - row0;
        if ((unsigned)rl < (unsigned)RPB2) atomicAdd(&cnt[rl], 1);
    }
    __syncthreads();

    // inclusive Hillis-Steele scan over 64 (cnt zero-padded)
    if (tid < 64) scn[tid] = (tid < RPB2) ? cnt[tid] : 0;
    __syncthreads();
    #pragma unroll
    for (int s = 1; s < 64; s <<= 1) {
        int t = (tid < 64 && tid >= s) ? scn[tid - s] : 0;
        __syncthreads();
        if (tid < 64) scn[tid] += t;
        __syncthreads();
    }
    if (tid < RPB2) wp[tid] = scn[tid] - cnt[tid];   // exclusive start
    __syncthreads();

    // scatter cols into per-row segments
    for (int e = tid; e < NPG * DEG; e += 256) {
        int rl = erow[ebase + e] - nbase - row0;
        if ((unsigned)rl < (unsigned)RPB2) {
            int p = atomicAdd(&wp[rl], 1);
            if (p < ECAP2) cols[p] = ecol[ebase + e];
        }
    }
    __syncthreads();

    const int wave = tid >> 6, lane = tid & 63;
    const int h    = lane >> 5;       // half-wave = node parity
    const int l32  = lane & 31;
    const int c4   = l32 * 4;         // float4 column offset
    const size_t N = NNODES;

    const float4 lwv = *reinterpret_cast<const float4*>(&lnw[c4]);
    const float4 lbv = *reinterpret_cast<const float4*>(&lnb[c4]);

    auto ln_store = [&](float4 v, float* dst) {
        float s  = v.x + v.y + v.z + v.w;
        float qq = v.x * v.x + v.y * v.y + v.z * v.z + v.w * v.w;
        #pragma unroll
        for (int m = 1; m < 32; m <<= 1) {
            s  += __shfl_xor(s, m);
            qq += __shfl_xor(qq, m);
        }
        const float mean = s * (1.f / 128.f);
        const float var  = fmaxf(qq * (1.f / 128.f) - mean * mean, 0.f);
        const float rs   = rsqrtf(var + LN_EPS);
        float4 o;
        o.x = (v.x - mean) * rs * lwv.x + lbv.x;
        o.y = (v.y - mean) * rs * lwv.y + lbv.y;
        o.z = (v.z - mean) * rs * lwv.z + lbv.z;
        o.w = (v.w - mean) * rs * lwv.w + lbv.w;
        *reinterpret_cast<float4*>(dst) = o;
    };

    // 4 waves x 2 half-waves cover 8 nodes per sweep; 50/8 -> 7 sweeps
    for (int n0 = wave * 2; n0 < RPB2; n0 += 8) {
        const int n = n0 + h;                     // n0 even, n <= 49 always
        const size_t gn = (size_t)(nbase + row0 + n);

        // own-row loads issued early (independent of the gather)
        float4 Sv = *reinterpret_cast<const float4*>(&Sbuf[gn * HID + c4]);
        float4 Iv = *reinterpret_cast<const float4*>(&Ibuf[gn * HID + c4]);
        float4 T  = *reinterpret_cast<const float4*>(&x[(3 * N + gn) * HID + c4]);

        // gather-accumulate AI (float4/lane = full 512B row, 4-deep ILP)
        int deg = cnt[n];
        int end = wp[n];            // == start + deg after scatter
        int j   = end - deg;
        float ax = 0.f, ay = 0.f, az = 0.f, aw = 0.f;
        for (; j + 4 <= end; j += 4) {
            int c0 = cols[j], c1 = cols[j + 1], c2 = cols[j + 2], c3 = cols[j + 3];
            float4 v0 = *reinterpret_cast<const float4*>(&Ibuf[(size_t)c0 * HID + c4]);
            float4 v1 = *reinterpret_cast<const float4*>(&Ibuf[(size_t)c1 * HID + c4]);
            float4 v2 = *reinterpret_cast<const float4*>(&Ibuf[(size_t)c2 * HID + c4]);
            float4 v3 = *reinterpret_cast<const float4*>(&Ibuf[(size_t)c3 * HID + c4]);
            ax += v0.x + v1.x + v2.x + v3.x;
            ay += v0.y + v1.y + v2.y + v3.y;
            az += v0.z + v1.z + v2.z + v3.z;
            aw += v0.w + v1.w + v2.w + v3.w;
        }
        for (; j < end; j++) {
            float4 v0 = *reinterpret_cast<const float4*>(&Ibuf[(size_t)cols[j] * HID + c4]);
            ax += v0.x; ay += v0.y; az += v0.z; aw += v0.w;
        }

        // beta/gam = cols 0,1 of tail row = lane h*32's float4
        const float beta = __shfl(T.x, h << 5);
        const float gam  = __shfl(T.y, h << 5);

        float4 dS, dI, dR;
        dS.x = -beta * (ax * Sv.x);
        dS.y = -beta * (ay * Sv.y);
        dS.z = -beta * (az * Sv.z);
        dS.w = -beta * (aw * Sv.w);
        dI.x = -dS.x - gam * Iv.x;
        dI.y = -dS.y - gam * Iv.y;
        dI.z = -dS.z - gam * Iv.z;
        dI.w = -dS.w - gam * Iv.w;
        dR.x = gam * Iv.x;
        dR.y = gam * Iv.y;
        dR.z = gam * Iv.z;
        dR.w = gam * Iv.w;

        ln_store(dS, &out[gn * HID + c4]);
        ln_store(dI, &out[(N + gn) * HID + c4]);
        ln_store(dR, &out[(2 * N + gn) * HID + c4]);
        *reinterpret_cast<float4*>(&out[(3 * N + gn) * HID + c4]) = T;
    }
}

// ---------------------------------------------------------------------------
// Fallback path (ws too small): original K2 (AI materialized) + K3.
// ---------------------------------------------------------------------------
#define BPG  8
#define RPB  (NPG / BPG)    // 125
#define ECAP 1280

__global__ __launch_bounds__(256) void k_aggregate(
    const float* __restrict__ I, const int* __restrict__ erow,
    const int* __restrict__ ecol, float* __restrict__ AI)
{
    __shared__ int cnt[RPB];
    __shared__ int wp[RPB];
    __shared__ int scan[256];
    __shared__ int cols[ECAP];

    const int g     = blockIdx.x / BPG;
    const int q     = blockIdx.x % BPG;
    const int row0  = q * RPB;
    const int nbase = g * NPG;
    const int ebase = g * (NPG * DEG);
    const int tid   = threadIdx.x;

    if (tid < RPB) cnt[tid] = 0;
    __syncthreads();

    for (int e = tid; e < NPG * DEG; e += 256) {
        int rl = erow[ebase + e] - nbase - row0;
        if ((unsigned)rl < (unsigned)RPB) atomicAdd(&cnt[rl], 1);
    }
    __syncthreads();

    int v = (tid < RPB) ? cnt[tid] : 0;
    scan[tid] = v;
    __syncthreads();
    #pragma unroll
    for (int s = 1; s < 256; s <<= 1) {
        int t = (tid >= s) ? scan[tid - s] : 0;
        __syncthreads();
        scan[tid] += t;
        __syncthreads();
    }
    if (tid < RPB) wp[tid] = scan[tid] - cnt[tid];
    __syncthreads();

    for (int e = tid; e < NPG * DEG; e += 256) {
        int rl = erow[ebase + e] - nbase - row0;
        if ((unsigned)rl < (unsigned)RPB) {
            int p = atomicAdd(&wp[rl], 1);
            if (p < ECAP) cols[p] = ecol[ebase + e];
        }
    }
    __syncthreads();

    const int wave = tid >> 6, lane = tid & 63;
    const int c = lane * 2;
    for (int n = wave; n < RPB; n += 4) {
        int deg = cnt[n];
        int end = wp[n];
        int j   = end - deg;
        float ax = 0.f, ay = 0.f;
        for (; j + 4 <= end; j += 4) {
            int c0 = cols[j], c1 = cols[j + 1], c2 = cols[j + 2], c3 = cols[j + 3];
            float2 v0 = *reinterpret_cast<const float2*>(&I[(size_t)c0 * HID + c]);
            float2 v1 = *reinterpret_cast<const float2*>(&I[(size_t)c1 * HID + c]);
            float2 v2 = *reinterpret_cast<const float2*>(&I[(size_t)c2 * HID + c]);
            float2 v3 = *reinterpret_cast<const float2*>(&I[(size_t)c3 * HID + c]);
            ax += v0.x + v1.x + v2.x + v3.x;
            ay += v0.y + v1.y + v2.y + v3.y;
        }
        for (; j < end; j++) {
            float2 v0 = *reinterpret_cast<const float2*>(&I[(size_t)cols[j] * HID + c]);
            ax += v0.x; ay += v0.y;
        }
        float2 o; o.x = ax; o.y = ay;
        *reinterpret_cast<float2*>(&AI[(size_t)(nbase + row0 + n) * HID + c]) = o;
    }
}

__global__ __launch_bounds__(256) void k_final(
    const float* __restrict__ x, const float* __restrict__ lnw,
    const float* __restrict__ lnb, float* __restrict__ out)
{
    const int wave = threadIdx.x >> 6;
    const int lane = threadIdx.x & 63;
    const size_t i = (size_t)blockIdx.x * 4 + wave;
    const int c    = lane * 2;
    const size_t N = NNODES;

    float2 S  = *reinterpret_cast<const float2*>(&out[i * HID + c]);
    float2 I2 = *reinterpret_cast<const float2*>(&out[(N + i) * HID + c]);
    float2 A  = *reinterpret_cast<const float2*>(&out[(2 * N + i) * HID + c]);

    const float beta = x[(3 * N + i) * HID + 0];
    const float gam  = x[(3 * N + i) * HID + 1];

    float2 dS, dI, dR;
    dS.x = -beta * (A.x * S.x);
    dS.y = -beta * (A.y * S.y);
    dI.x = -dS.x - gam * I2.x;
    dI.y = -dS.y - gam * I2.y;
    dR.x = gam * I2.x;
    dR.y = gam * I2.y;

    const float2 lw = *reinterpret_cast<const float2*>(&lnw[c]);
    const float2 lb = *reinterpret_cast<const float2*>(&lnb[c]);

    auto ln_store = [&](float2 v, float* dst) {
        float s = v.x + v.y;
        #pragma unroll
        for (int m = 1; m < 64; m <<= 1) s += __shfl_xor(s, m);
        const float mean = s * (1.f / 128.f);
        const float dx = v.x - mean, dy = v.y - mean;
        float q = dx * dx + dy * dy;
        #pragma unroll
        for (int m = 1; m < 64; m <<= 1) q += __shfl_xor(q, m);
        const float rs = rsqrtf(q * (1.f / 128.f) + LN_EPS);
        float2 o;
        o.x = dx * rs * lw.x + lb.x;
        o.y = dy * rs * lw.y + lb.y;
        *reinterpret_cast<float2*>(dst) = o;
    };

    ln_store(dS, &out[i * HID + c]);
    ln_store(dI, &out[(N + i) * HID + c]);
    ln_store(dR, &out[(2 * N + i) * HID + c]);

    const float2 t2 =
        *reinterpret_cast<const float2*>(&x[(3 * N + i) * HID + c]);
    *reinterpret_cast<float2*>(&out[(3 * N + i) * HID + c]) = t2;
}

// ---------------------------------------------------------------------------
extern "C" void kernel_launch(void* const* d_in, const int* in_sizes, int n_in,
                              void* d_out, int out_size, void* d_ws,
                              size_t ws_size, hipStream_t stream)
{
    // inputs: 0:t 1:x 2:edge_row 3:edge_col 4:W 5:b 6:ln_w 7:ln_b
    const float* x   = (const float*)d_in[1];
    const int* erow  = (const int*)d_in[2];
    const int* ecol  = (const int*)d_in[3];
    const float* W   = (const float*)d_in[4];
    const float* b   = (const float*)d_in[5];
    const float* lnw = (const float*)d_in[6];
    const float* lnb = (const float*)d_in[7];
    float* out = (float*)d_out;

    const int nrows = 2 * NNODES;                    // R rows never needed
    const size_t ineed = (size_t)NNODES * HID * sizeof(float);

    if (d_ws != nullptr && ws_size >= ineed) {
        // Fused path: I rows -> workspace; AI never materialized.
        float* Iws = (float*)d_ws;
        k_gemm_relu<<<(nrows + K1_ROWS - 1) / K1_ROWS, 256, 0, stream>>>(
            x, W, b, out, Iws, nrows);
        k_agg_final<<<NGRAPH * BPG2, 256, 0, stream>>>(
            x, out, Iws, erow, ecol, lnw, lnb, out);
    } else {
        // Fallback: original 3-kernel path, I rows in out[N..2N).
        float* Iptr  = out + (size_t)NNODES * HID;
        float* AIptr = out + (size_t)2 * NNODES * HID;
        k_gemm_relu<<<(nrows + K1_ROWS - 1) / K1_ROWS, 256, 0, stream>>>(
            x, W, b, out, Iptr, nrows);
        k_aggregate<<<NGRAPH * BPG, 256, 0, stream>>>(Iptr, erow, ecol, AIptr);
        k_final<<<NNODES / 4, 256, 0, stream>>>(x, lnw, lnb, out);
    }
}